// Round 2
// baseline (497.136 us; speedup 1.0000x reference)
//
#include <hip/hip_runtime.h>

// Problem sizes (fixed by reference)
#define B_N   8192
#define S_N   512
#define F_N   64
#define R_N   4096
#define D_N   256
#define T_N   16

// K2 (score/argmin GEMM) tiling
#define K2_BM 64            // rows per block
#define K2_RN 256           // codebook cols per block
#define K2_KC 16            // k-chunk
#define K2_NJ (R_N / K2_RN) // 16 col tiles
#define K2_KT (D_N / K2_KC) // 16 k chunks

__device__ __forceinline__ void gld_lds16(const float* g, float* l) {
  __builtin_amdgcn_global_load_lds(
      (const __attribute__((address_space(1))) void*)g,
      (__attribute__((address_space(3))) void*)l, 16, 0, 0);
}

// ---------------- K0a: rsqh[r] = 0.5 * sum_k register[r][k]^2 ----------------
__global__ __launch_bounds__(256) void k_rsq(const float* __restrict__ reg,
                                             float* __restrict__ rsqh) {
  const int t = threadIdx.x;
  const int lane = t & 63;
  const int r = blockIdx.x * 4 + (t >> 6);
  const float4 v = *(const float4*)&reg[(size_t)r * D_N + lane * 4];
  float s = v.x * v.x + v.y * v.y + v.z * v.z + v.w * v.w;
#pragma unroll
  for (int m = 32; m >= 1; m >>= 1) s += __shfl_xor(s, m);
  if (lane == 0) rsqh[r] = 0.5f * s;
}

// ---------------- K0b: regT[k][r] = register[r][k] ----------------
__global__ __launch_bounds__(256) void k_transpose(const float* __restrict__ reg,
                                                   float* __restrict__ regT) {
  __shared__ float tile[64][65];
  const int t = threadIdx.x;
  const int r0 = blockIdx.x * 64;
  const int k0 = blockIdx.y * 64;
  const int a = t >> 2;  // 0..63
  const int q = t & 3;   // 0..3
#pragma unroll
  for (int i = 0; i < 4; ++i) {
    const int c = q * 16 + i * 4;
    const float4 v = *(const float4*)&reg[(size_t)(r0 + a) * D_N + k0 + c];
    tile[a][c + 0] = v.x; tile[a][c + 1] = v.y;
    tile[a][c + 2] = v.z; tile[a][c + 3] = v.w;
  }
  __syncthreads();
#pragma unroll
  for (int i = 0; i < 4; ++i) {
    const int rr = q * 16 + i * 4;
    float4 o;
    o.x = tile[rr + 0][a]; o.y = tile[rr + 1][a];
    o.z = tile[rr + 2][a]; o.w = tile[rr + 3][a];
    *(float4*)&regT[(size_t)(k0 + a) * R_N + r0 + rr] = o;
  }
}

// ---------------- K1: temporal mean over S + projection to xe[b][d] ----------------
__global__ __launch_bounds__(256) void k_meanproj(const float* __restrict__ x,
                                                  const float* __restrict__ W,
                                                  const float* __restrict__ bias,
                                                  float* __restrict__ xe) {
  __shared__ __align__(16) float4 red[256];
  __shared__ __align__(16) float xm[F_N];
  const int b = blockIdx.x;
  const int t = threadIdx.x;
  const float* xb = x + (size_t)b * (S_N * F_N);
  const int sg = t >> 4;         // 0..15 (s subgroup)
  const int f4 = (t & 15) * 4;   // feature base
  float4 acc = make_float4(0.f, 0.f, 0.f, 0.f);
#pragma unroll 4
  for (int s = sg; s < S_N; s += 16) {
    const float4 v = *(const float4*)&xb[s * F_N + f4];
    acc.x += v.x; acc.y += v.y; acc.z += v.z; acc.w += v.w;
  }
  red[t] = acc;
  __syncthreads();
  if (t < 16) {
    float4 a = red[t];
#pragma unroll
    for (int g = 1; g < 16; ++g) {
      const float4 o = red[g * 16 + t];
      a.x += o.x; a.y += o.y; a.z += o.z; a.w += o.w;
    }
    const float inv = 1.0f / (float)S_N;
    xm[t * 4 + 0] = a.x * inv; xm[t * 4 + 1] = a.y * inv;
    xm[t * 4 + 2] = a.z * inv; xm[t * 4 + 3] = a.w * inv;
  }
  __syncthreads();
  // projection: thread t computes xe[b][t]
  float p = bias[t];
#pragma unroll
  for (int k4 = 0; k4 < F_N / 4; ++k4) {
    const float4 wv = *(const float4*)&W[(size_t)t * F_N + k4 * 4];
    const float4 xv = *(const float4*)&xm[k4 * 4];
    p = fmaf(wv.x, xv.x, p);
    p = fmaf(wv.y, xv.y, p);
    p = fmaf(wv.z, xv.z, p);
    p = fmaf(wv.w, xv.w, p);
  }
  xe[(size_t)b * D_N + t] = p;
}

// ---------------- K2: score = 0.5*||reg_r||^2 - xe.reg_r ; per-tile argmin ----------------
__global__ __launch_bounds__(256, 2) void k_score(const float* __restrict__ xe,
                                                  const float* __restrict__ regT,
                                                  const float* __restrict__ rsqh,
                                                  float* __restrict__ pval,
                                                  int* __restrict__ pidx) {
  __shared__ __align__(16) float lA[2][K2_BM][K2_KC];  // 8 KB  (xe tile, [m][k])
  __shared__ __align__(16) float lB[2][K2_KC][K2_RN];  // 32 KB (regT tile, [k][c])
  const int t = threadIdx.x;
  const int w = t >> 6;     // wave 0..3 -> row group
  const int lane = t & 63;  // -> col group
  const int jb = blockIdx.x;            // col tile 0..15
  const int bm0 = blockIdx.y * K2_BM;   // row base
  const int m0 = w * 16;
  const int c0 = lane * 4;

  float acc[16][4];
#pragma unroll
  for (int mm = 0; mm < 16; ++mm)
#pragma unroll
    for (int cc = 0; cc < 4; ++cc) acc[mm][cc] = 0.f;

  auto stage = [&](int ch, int buf) {
    const int k0 = ch * K2_KC;
    // B: 16 rows of regT chunk; wave w stages rows w*4..w*4+3 (1 KB each)
#pragma unroll
    for (int i = 0; i < 4; ++i) {
      const int kr = w * 4 + i;
      gld_lds16(&regT[(size_t)(k0 + kr) * R_N + jb * K2_RN + lane * 4],
                &lB[buf][kr][0]);
    }
    // A: 64 rows x 16 k; wave w stages rows w*16..w*16+15 (1 KB, 64B rows)
    gld_lds16(&xe[(size_t)(bm0 + w * 16 + (lane >> 2)) * D_N + k0 + (lane & 3) * 4],
              &lA[buf][w * 16][0]);
  };

  stage(0, 0);
  __syncthreads();  // drains vmcnt before compute
  int cur = 0;
  for (int ch = 0; ch < K2_KT; ++ch) {
    if (ch + 1 < K2_KT) stage(ch + 1, cur ^ 1);
#pragma unroll
    for (int kk = 0; kk < K2_KC; kk += 4) {
      float bf[4][4];  // [k][c]
#pragma unroll
      for (int j = 0; j < 4; ++j) {
        const float4 v = *(const float4*)&lB[cur][kk + j][c0];  // 16B-stride, conflict-free
        bf[j][0] = v.x; bf[j][1] = v.y; bf[j][2] = v.z; bf[j][3] = v.w;
      }
#pragma unroll
      for (int h = 0; h < 2; ++h) {
        float af[8][4];  // [m][k]
#pragma unroll
        for (int mm = 0; mm < 8; ++mm) {
          const float4 v = *(const float4*)&lA[cur][m0 + h * 8 + mm][kk];  // broadcast
          af[mm][0] = v.x; af[mm][1] = v.y; af[mm][2] = v.z; af[mm][3] = v.w;
        }
#pragma unroll
        for (int mm = 0; mm < 8; ++mm)
#pragma unroll
          for (int j = 0; j < 4; ++j)
#pragma unroll
            for (int cc = 0; cc < 4; ++cc)
              acc[h * 8 + mm][cc] = fmaf(af[mm][j], bf[j][cc], acc[h * 8 + mm][cc]);
      }
    }
    __syncthreads();  // waits next-stage vmcnt + all readers of cur
    cur ^= 1;
  }

  // epilogue: score = 0.5*||reg||^2 - dot  (monotone surrogate of distance)
  const float4 rq4 = *(const float4*)&rsqh[jb * K2_RN + c0];
  const float rqa[4] = {rq4.x, rq4.y, rq4.z, rq4.w};
#pragma unroll
  for (int mm = 0; mm < 16; ++mm) {
    float bv = rqa[0] - acc[mm][0];
    int bi = jb * K2_RN + c0;
#pragma unroll
    for (int cc = 1; cc < 4; ++cc) {
      const float v2 = rqa[cc] - acc[mm][cc];
      if (v2 < bv) { bv = v2; bi = jb * K2_RN + c0 + cc; }  // strict < keeps lowest idx
    }
#pragma unroll
    for (int m = 32; m >= 1; m >>= 1) {
      const float ov = __shfl_xor(bv, m);
      const int oi = __shfl_xor(bi, m);
      if (ov < bv || (ov == bv && oi < bi)) { bv = ov; bi = oi; }
    }
    if (lane == 0) {
      pval[(size_t)(bm0 + m0 + mm) * K2_NJ + jb] = bv;
      pidx[(size_t)(bm0 + m0 + mm) * K2_NJ + jb] = bi;
    }
  }
}

// ---------------- K3: reduce partials, gather codebook row, write Xd + per-b loss ----------------
__global__ __launch_bounds__(256) void k_final(const float* __restrict__ reg,
                                               const float* __restrict__ xe,
                                               const float* __restrict__ pval,
                                               const int* __restrict__ pidx,
                                               float* __restrict__ out,
                                               float* __restrict__ lossArr) {
  const int b = blockIdx.x;
  const int t = threadIdx.x;
  const int lane = t & 63;
  const int w = t >> 6;
  // argmin over 16 tile partials (every 16-lane group does the same reduce)
  float bv = pval[(size_t)b * K2_NJ + (t & 15)];
  int bi = pidx[(size_t)b * K2_NJ + (t & 15)];
#pragma unroll
  for (int m = 8; m >= 1; m >>= 1) {
    const float ov = __shfl_xor(bv, m);
    const int oi = __shfl_xor(bi, m);
    if (ov < bv || (ov == bv && oi < bi)) { bv = ov; bi = oi; }
  }
  const int d4 = lane * 4;
  const float4 sel = *(const float4*)&reg[(size_t)bi * D_N + d4];
  // tile selected row across T_N tokens (1 KB contiguous per wave-instr)
#pragma unroll
  for (int tt0 = 0; tt0 < T_N / 4; ++tt0) {
    const int tt = tt0 * 4 + w;
    *(float4*)&out[(size_t)b * (T_N * D_N) + (size_t)tt * D_N + d4] = sel;
  }
  // per-b loss partial (each wave computes the full row sum; wave0 writes)
  const float4 xv = *(const float4*)&xe[(size_t)b * D_N + d4];
  const float ex = xv.x - sel.x, ey = xv.y - sel.y, ez = xv.z - sel.z, ew = xv.w - sel.w;
  float p = ex * ex + ey * ey + ez * ez + ew * ew;
#pragma unroll
  for (int m = 32; m >= 1; m >>= 1) p += __shfl_xor(p, m);
  if (t == 0) lossArr[b] = p;
}

// ---------------- K4: loss = mean over B ----------------
__global__ __launch_bounds__(256) void k_loss(const float* __restrict__ lossArr,
                                              float* __restrict__ out) {
  __shared__ float ws4[4];
  const int t = threadIdx.x;
  float s = 0.f;
  for (int i = t; i < B_N; i += 256) s += lossArr[i];
#pragma unroll
  for (int m = 32; m >= 1; m >>= 1) s += __shfl_xor(s, m);
  if ((t & 63) == 0) ws4[t >> 6] = s;
  __syncthreads();
  if (t == 0)
    out[(size_t)B_N * T_N * D_N] = (ws4[0] + ws4[1] + ws4[2] + ws4[3]) / (float)B_N;
}

extern "C" void kernel_launch(void* const* d_in, const int* in_sizes, int n_in,
                              void* d_out, int out_size, void* d_ws, size_t ws_size,
                              hipStream_t stream) {
  const float* x    = (const float*)d_in[0];
  const float* W    = (const float*)d_in[1];
  const float* bias = (const float*)d_in[2];
  const float* reg  = (const float*)d_in[3];
  float* out = (float*)d_out;
  float* ws  = (float*)d_ws;

  // workspace layout (floats): all regions fully rewritten every call
  float* xe      = ws;                            // 8192*256   = 2,097,152
  float* regT    = xe + (size_t)B_N * D_N;        // 256*4096   = 1,048,576
  float* rsqh    = regT + (size_t)D_N * R_N;      // 4096
  float* pval    = rsqh + R_N;                    // 8192*16
  int*   pidx    = (int*)(pval + (size_t)B_N * K2_NJ);  // 8192*16
  float* lossArr = (float*)pidx + (size_t)B_N * K2_NJ;  // 8192

  k_rsq<<<dim3(R_N / 4), dim3(256), 0, stream>>>(reg, rsqh);
  k_transpose<<<dim3(R_N / 64, D_N / 64), dim3(256), 0, stream>>>(reg, regT);
  k_meanproj<<<dim3(B_N), dim3(256), 0, stream>>>(x, W, bias, xe);
  k_score<<<dim3(K2_NJ, B_N / K2_BM), dim3(256), 0, stream>>>(xe, regT, rsqh, pval, pidx);
  k_final<<<dim3(B_N), dim3(256), 0, stream>>>(reg, xe, pval, pidx, out, lossArr);
  k_loss<<<dim3(1), dim3(256), 0, stream>>>(lossArr, out);
}